// Round 5
// baseline (567.820 us; speedup 1.0000x reference)
//
#include <hip/hip_runtime.h>
#include <hip/hip_bf16.h>

// Equivariant decoder: r=|v| -> MLP(fp32 tiled GEMMs) -> r_dec bf16
//   -> t=einsum('bi,ijp') bf16 MFMA, counted-vmcnt 4-buffer pipeline (T3+T4+T5)
//   -> out_vec=einsum('bjp,bjm')/C fused in-register -> [P x 1o | Q zeros]
// Workspace (83.4 MB, same proven layout as round 4):
//   [0, 67108864)         Wtp bf16, 32x32x16 A-fragment order
//   [67108864, 67633152)  r_dec bf16 [1024][256]
//   [67633152, 70778880)  vT fp32 [256 j][3 m][1024 b]
//   [70778880, 83361792)  part bf16 [4 js][1024 b][1536]  (MLP temps overlap)

#define N_G   1024
#define C_DIM 256
#define P_DIM 512
#define F_DIM 768
#define OUT_STRIDE 6656
#define VEC_LEN 1536

typedef short  short8  __attribute__((ext_vector_type(8)));
typedef float  f32x16  __attribute__((ext_vector_type(16)));

#define GLOAD_LDS16(GP, LP)                                                    \
  __builtin_amdgcn_global_load_lds(                                            \
      (const __attribute__((address_space(1))) void*)(GP),                     \
      (__attribute__((address_space(3))) void*)(LP), 16, 0, 0)

static __device__ __forceinline__ unsigned short f32_bf16(float f){
  unsigned u = __builtin_bit_cast(unsigned, f);
  u = (u + 0x7fffu + ((u >> 16) & 1u)) >> 16;   // RNE
  return (unsigned short)u;
}
static __device__ __forceinline__ float bf16_f32(unsigned short u){
  return __builtin_bit_cast(float, (unsigned)u << 16);
}
static __device__ __forceinline__ float gelu_tanh(float x){
  float u = 0.7978845608028654f * (x + 0.044715f * x * x * x);
  return 0.5f * x * (1.0f + tanhf(u));
}

// ---------------- prepack: Wtp fp32 [i=256][j=256][p=512] -> bf16 A-fragment order
__global__ __launch_bounds__(256) void k_prepack(const float* __restrict__ wtp,
                                                 unsigned short* __restrict__ frag){
  int tid  = blockIdx.x * 256 + threadIdx.x;
  int unit = tid >> 6, lane = tid & 63;
  int j  = unit >> 8;
  int pt = (unit >> 4) & 15;
  int ik = unit & 15;
  int p  = pt * 32 + (lane & 31);
  int i0 = ik * 16 + (lane >> 5) * 8;
  const float* src = wtp + (size_t)i0 * (C_DIM * P_DIM) + j * P_DIM + p;
  short8 v;
  #pragma unroll
  for (int e = 0; e < 8; ++e)
    v[e] = (short)f32_bf16(src[(size_t)e * (C_DIM * P_DIM)]);
  *reinterpret_cast<short8*>(frag + (size_t)unit * 512 + lane * 8) = v;
}

// ---------------- r = per-channel vector norms
__global__ __launch_bounds__(256) void k_norm(const float* __restrict__ enc,
                                              float* __restrict__ r){
  int b = blockIdx.x, t = threadIdx.x;
  const float* e = enc + (size_t)b * F_DIM + t * 3;
  r[(size_t)b * C_DIM + t] = sqrtf(e[0]*e[0] + e[1]*e[1] + e[2]*e[2]);
}

// ---------------- vT[j][m][b] = enc[b][3j+m]
__global__ __launch_bounds__(256) void k_vt(const float* __restrict__ enc,
                                            float* __restrict__ vT){
  int tid = blockIdx.x * 256 + threadIdx.x;
  int b  = tid & 1023;
  int jm = tid >> 10;
  int j  = jm / 3, m = jm - j * 3;
  vT[(size_t)j * 3072 + m * 1024 + b] = enc[(size_t)b * F_DIM + j * 3 + m];
}

// ---------------- tiled fp32 GEMM: C = A@B + bias. BM=32,BN=64,BK=64; 256 thr.
// LDS padding chosen conflict-free: Ast stride 33 (writes 2-way, reads broadcast
// via ds_read2_b32), Bs stride 68 (reads 2-way, b128-aligned).
template<bool OBF>
__global__ __launch_bounds__(256) void k_gemm(const float* __restrict__ A,
    const float* __restrict__ B, const float* __restrict__ bias,
    float* __restrict__ C, unsigned short* __restrict__ Cb,
    int M, int N, int K){
  __shared__ __align__(16) float Ast[64][33];
  __shared__ __align__(16) float Bs[64][68];
  int nbc = N >> 6;
  int mb = blockIdx.x / nbc, nb = blockIdx.x % nbc;
  int m0 = mb * 32, n0 = nb * 64;
  int t  = threadIdx.x;
  int tr = t >> 4, tc = t & 15;

  float acc[2][4];
  #pragma unroll
  for (int i = 0; i < 2; ++i)
    #pragma unroll
    for (int q = 0; q < 4; ++q) acc[i][q] = 0.f;

  for (int kc = 0; kc < K; kc += 64){
    { // stage A[32][64] transposed: thread reads 8 floats of row m, scatters to Ast[k][m]
      int m = t >> 3, k0 = (t & 7) * 8;
      const float* ap = A + (size_t)(m0 + m) * K + kc + k0;
      float4 a0 = *reinterpret_cast<const float4*>(ap);
      float4 a1 = *reinterpret_cast<const float4*>(ap + 4);
      Ast[k0+0][m] = a0.x; Ast[k0+1][m] = a0.y; Ast[k0+2][m] = a0.z; Ast[k0+3][m] = a0.w;
      Ast[k0+4][m] = a1.x; Ast[k0+5][m] = a1.y; Ast[k0+6][m] = a1.z; Ast[k0+7][m] = a1.w;
    }
    { // stage B[64][64]
      int kk = t >> 2, nc = (t & 3) * 16;
      const float* bp = B + (size_t)(kc + kk) * N + n0 + nc;
      float4* d = reinterpret_cast<float4*>(&Bs[kk][nc]);
      d[0] = reinterpret_cast<const float4*>(bp)[0];
      d[1] = reinterpret_cast<const float4*>(bp)[1];
      d[2] = reinterpret_cast<const float4*>(bp)[2];
      d[3] = reinterpret_cast<const float4*>(bp)[3];
    }
    __syncthreads();
    #pragma unroll 16
    for (int kk = 0; kk < 64; ++kk){
      float a0 = Ast[kk][tr * 2], a1 = Ast[kk][tr * 2 + 1];
      float4 bv = *reinterpret_cast<const float4*>(&Bs[kk][tc * 4]);
      acc[0][0] += a0*bv.x; acc[0][1] += a0*bv.y; acc[0][2] += a0*bv.z; acc[0][3] += a0*bv.w;
      acc[1][0] += a1*bv.x; acc[1][1] += a1*bv.y; acc[1][2] += a1*bv.z; acc[1][3] += a1*bv.w;
    }
    __syncthreads();
  }

  #pragma unroll
  for (int i = 0; i < 2; ++i){
    int row = m0 + tr * 2 + i;
    #pragma unroll
    for (int q = 0; q < 4; ++q){
      int col = n0 + tc * 4 + q;
      float val = acc[i][q] + bias[col];
      if (OBF) Cb[(size_t)row * N + col] = f32_bf16(val);
      else     C [(size_t)row * N + col] = val;
    }
  }
}

// ---------------- LayerNorm + GELU, wave per row
__global__ __launch_bounds__(256) void k_ln(const float* __restrict__ X,
    const float* __restrict__ g, const float* __restrict__ be,
    float* __restrict__ Y){
  int w = threadIdx.x >> 6, lane = threadIdx.x & 63;
  int row = blockIdx.x * 4 + w;
  const float* x = X + (size_t)row * F_DIM;
  float v[12];
  float s = 0.f, s2 = 0.f;
  #pragma unroll
  for (int i = 0; i < 12; ++i){
    v[i] = x[lane + i * 64];
    s += v[i]; s2 += v[i] * v[i];
  }
  #pragma unroll
  for (int off = 32; off; off >>= 1){ s += __shfl_down(s, off); s2 += __shfl_down(s2, off); }
  s = __shfl(s, 0); s2 = __shfl(s2, 0);
  float mu = s * (1.0f / F_DIM);
  float rs = rsqrtf(s2 * (1.0f / F_DIM) - mu * mu + 1e-5f);
  float* y = Y + (size_t)row * F_DIM;
  #pragma unroll
  for (int i = 0; i < 12; ++i){
    int c = lane + i * 64;
    y[c] = gelu_tanh((v[i] - mu) * rs * g[c] + be[c]);
  }
}

// ---------------- main fused TP: counted-vmcnt 4-buffer pipeline.
// grid 256 = pt(16) x bblk(4) x js(4); 512 thr = 8 waves x (32p x 32b); 64 j/block.
// Stage-ahead-3 into As[4]; per j: waitcnt(N)+s_barrier (no full drain), 16 ds_read_b128
// + 16 MFMA (setprio-wrapped), 48 VALU FMAs with register-batched v (8 j per batch,
// loaded at group heads so the vmcnt FIFO count stays provable: 28 on the two iters
// after a 24-load v-batch, 4 steady-state, 4/2/0 tail).
__global__ __launch_bounds__(512, 2) void k_tp(const unsigned short* __restrict__ frag,
    const unsigned short* __restrict__ rdec, const float* __restrict__ vT,
    unsigned short* __restrict__ part){
  __shared__ __align__(16) unsigned short As[4][8192];   // 4 x 16KB j-tiles
  int bx   = blockIdx.x;
  int pt   = bx & 15;
  int bblk = (bx >> 4) & 3;
  int js   = bx >> 6;
  int w    = threadIdx.x >> 6;
  int lane = threadIdx.x & 63;
  int g    = lane >> 5;
  int b    = bblk * 256 + w * 32 + (lane & 31);

  short8 bf[16];
  #pragma unroll
  for (int ik = 0; ik < 16; ++ik)
    bf[ik] = *reinterpret_cast<const short8*>(rdec + (size_t)b * C_DIM + ik * 16 + g * 8);

  float oacc[48];
  #pragma unroll
  for (int q = 0; q < 48; ++q) oacc[q] = 0.f;

  float vreg[8][3];
  int j0 = js * 64;

  #define STAGE(BUF, J) do {                                                        \
    _Pragma("unroll")                                                               \
    for (int uu = 0; uu < 2; ++uu){                                                 \
      int u = w * 2 + uu;                                                           \
      const unsigned short* gp = frag + ((size_t)(((J) * 16 + pt) * 16 + u)) * 512  \
                                 + lane * 8;                                        \
      GLOAD_LDS16(gp, &As[BUF][u * 512]);                                           \
    } } while (0)

  #define VLOAD(JB) do {                                                            \
    const float* vp_ = vT + (size_t)(JB) * 3072 + b;                                \
    _Pragma("unroll")                                                               \
    for (int q_ = 0; q_ < 8; ++q_){                                                 \
      vreg[q_][0] = vp_[(size_t)q_ * 3072];                                         \
      vreg[q_][1] = vp_[(size_t)q_ * 3072 + 1024];                                  \
      vreg[q_][2] = vp_[(size_t)q_ * 3072 + 2048];                                  \
    } } while (0)

  #define WAITN(N) asm volatile("s_waitcnt vmcnt(" #N ")" ::: "memory")

  // One j-iteration. T may be runtime; TQ/WN must be literals.
  #define TPITER(T, TQ, WN, DOSTAGE, DOVL, VJ) do {                                 \
    WAITN(WN);                                                                      \
    __builtin_amdgcn_s_barrier();                                                   \
    __builtin_amdgcn_sched_barrier(0);                                              \
    if (DOVL) VLOAD(VJ);                                                            \
    if (DOSTAGE) STAGE(((T) + 3) & 3, j0 + (T) + 3);                                \
    const unsigned short* ap_ = &As[(T) & 3][lane * 8];                             \
    f32x16 acc_ = {};                                                               \
    __builtin_amdgcn_s_setprio(1);                                                  \
    _Pragma("unroll")                                                               \
    for (int ik_ = 0; ik_ < 16; ++ik_){                                             \
      short8 a_ = *reinterpret_cast<const short8*>(ap_ + (size_t)ik_ * 512);        \
      acc_ = __builtin_amdgcn_mfma_f32_32x32x16_bf16(a_, bf[ik_], acc_, 0, 0, 0);   \
    }                                                                               \
    __builtin_amdgcn_s_setprio(0);                                                  \
    _Pragma("unroll")                                                               \
    for (int r_ = 0; r_ < 16; ++r_){                                                \
      oacc[r_*3+0] += acc_[r_] * vreg[TQ][0];                                       \
      oacc[r_*3+1] += acc_[r_] * vreg[TQ][1];                                       \
      oacc[r_*3+2] += acc_[r_] * vreg[TQ][2];                                       \
    } } while (0)

  // prologue: v-batch 0 first (oldest in FIFO), then 3 staged tiles
  VLOAD(j0);
  STAGE(0, j0); STAGE(1, j0 + 1); STAGE(2, j0 + 2);

  // group 0: batch was loaded in prologue (older than all stages) -> all waits 4
  TPITER(0,0,4,1,0,0); TPITER(1,1,4,1,0,0); TPITER(2,2,4,1,0,0); TPITER(3,3,4,1,0,0);
  TPITER(4,4,4,1,0,0); TPITER(5,5,4,1,0,0); TPITER(6,6,4,1,0,0); TPITER(7,7,4,1,0,0);

  // groups 1..6: v-batch at head; batch is younger than stages t+1,t+2 for the
  // next two iters -> vmcnt(28) there, else vmcnt(4)
  for (int Gq = 1; Gq < 7; ++Gq){
    int tb = Gq * 8;
    TPITER(tb+0,0, 4,1,1, j0 + tb);
    TPITER(tb+1,1,28,1,0,0);
    TPITER(tb+2,2,28,1,0,0);
    TPITER(tb+3,3, 4,1,0,0);
    TPITER(tb+4,4, 4,1,0,0);
    TPITER(tb+5,5, 4,1,0,0);
    TPITER(tb+6,6, 4,1,0,0);
    TPITER(tb+7,7, 4,1,0,0);
  }

  // group 7 (t=56..63): last stage at t=60 (tile 63); draining tail 4/2/0
  TPITER(56,0, 4,1,1, j0 + 56);
  TPITER(57,1,28,1,0,0);
  TPITER(58,2,28,1,0,0);
  TPITER(59,3, 4,1,0,0);
  TPITER(60,4, 4,1,0,0);
  TPITER(61,5, 4,0,0,0);
  TPITER(62,6, 2,0,0,0);
  TPITER(63,7, 0,0,0,0);

  unsigned short* pb = part + ((size_t)js * N_G + b) * VEC_LEN;
  #pragma unroll
  for (int r = 0; r < 16; ++r){
    int p = pt * 32 + (r & 3) + 8 * (r >> 2) + 4 * g;   // verified C/D row map (m74/m101)
    pb[p*3+0] = f32_bf16(oacc[r*3+0]);
    pb[p*3+1] = f32_bf16(oacc[r*3+1]);
    pb[p*3+2] = f32_bf16(oacc[r*3+2]);
  }
}

// ---------------- reduce 4 bf16 j-partials * (1/C), write structural zeros
__global__ __launch_bounds__(256) void k_reduce(const unsigned short* __restrict__ part,
                                                float* __restrict__ out){
  int idx = blockIdx.x * 256 + threadIdx.x;
  if (idx >= N_G * OUT_STRIDE) return;
  int b = idx / OUT_STRIDE;
  int q = idx - b * OUT_STRIDE;
  float val = 0.f;
  if (q < VEC_LEN){
    size_t base = (size_t)b * VEC_LEN + q;
    const size_t st = (size_t)N_G * VEC_LEN;
    val = (bf16_f32(part[base]) + bf16_f32(part[base + st]) +
           bf16_f32(part[base + 2*st]) + bf16_f32(part[base + 3*st])) * (1.0f / C_DIM);
  }
  out[idx] = val;
}

extern "C" void kernel_launch(void* const* d_in, const int* in_sizes, int n_in,
                              void* d_out, int out_size, void* d_ws, size_t ws_size,
                              hipStream_t stream){
  const float* enc  = (const float*)d_in[0];
  const float* W0   = (const float*)d_in[1];
  const float* b0   = (const float*)d_in[2];
  const float* g0   = (const float*)d_in[3];
  const float* be0  = (const float*)d_in[4];
  const float* W1   = (const float*)d_in[5];
  const float* b1   = (const float*)d_in[6];
  const float* g1   = (const float*)d_in[7];
  const float* be1  = (const float*)d_in[8];
  const float* Wout = (const float*)d_in[9];
  const float* bout = (const float*)d_in[10];
  const float* Wtp  = (const float*)d_in[11];
  float* out = (float*)d_out;

  char* ws = (char*)d_ws;
  unsigned short* frag = (unsigned short*)(ws);                 // 64 MB
  unsigned short* rdec = (unsigned short*)(ws + 67108864);      // 512 KB
  float*          vT   = (float*)(ws + 67633152);               // 3 MB
  unsigned short* part = (unsigned short*)(ws + 70778880);      // 12.6 MB
  float* rbuf = (float*)(ws + 70778880);                        // MLP temps overlap part
  float* bufA = (float*)(ws + 70778880 + 1048576);
  float* bufB = (float*)(ws + 70778880 + 1048576 + 3145728);

  hipLaunchKernelGGL(k_prepack, dim3(16384), dim3(256), 0, stream, Wtp, frag);
  hipLaunchKernelGGL(k_norm,    dim3(N_G),   dim3(256), 0, stream, enc, rbuf);
  hipLaunchKernelGGL(k_vt,      dim3(3072),  dim3(256), 0, stream, enc, vT);
  hipLaunchKernelGGL((k_gemm<false>), dim3(32 * 12), dim3(256), 0, stream,
                     rbuf, W0, b0, bufA, rdec, N_G, F_DIM, C_DIM);
  hipLaunchKernelGGL(k_ln,      dim3(256),   dim3(256), 0, stream, bufA, g0, be0, bufB);
  hipLaunchKernelGGL((k_gemm<false>), dim3(32 * 12), dim3(256), 0, stream,
                     bufB, W1, b1, bufA, rdec, N_G, F_DIM, F_DIM);
  hipLaunchKernelGGL(k_ln,      dim3(256),   dim3(256), 0, stream, bufA, g1, be1, bufB);
  hipLaunchKernelGGL((k_gemm<true>),  dim3(32 * 4),  dim3(256), 0, stream,
                     bufB, Wout, bout, bufA, rdec, N_G, C_DIM, F_DIM);
  hipLaunchKernelGGL(k_tp,      dim3(256),   dim3(512), 0, stream, frag, rdec, vT, part);
  hipLaunchKernelGGL(k_reduce,  dim3((N_G * OUT_STRIDE + 255) / 256), dim3(256), 0, stream,
                     part, out);
}